// Round 4
// baseline (344.554 us; speedup 1.0000x reference)
//
#include <hip/hip_runtime.h>
#include <math.h>

#define B_ 128
#define D_ 128
#define P_ 4
#define M_ 100000
#define K_ 10
#define SCALE_ 10.0f
#define WPP 512                 // waves per p in k_neg
#define NT16 6250               // 16-row tiles per p (100000/16, exact)
#define NEG_BLOCKS 512          // 128 blocks per p x 4 waves = 512 waves per p
#define MMD_BLOCKS 128
#define POS_BLOCKS 128          // 512 (p,b) pairs / 4 waves
#define D2_CUT 120.0f           // d2 >= 120 -> exp(-10*sqrt(d2)) == 0.0f exactly (2^-158)

typedef short bf16x8 __attribute__((ext_vector_type(8)));
typedef float floatx4 __attribute__((ext_vector_type(4)));

// pack two fp32 -> two bf16 (truncate) in one v_perm_b32
__device__ inline unsigned pack_bf16_trunc(unsigned f0, unsigned f1) {
    return __builtin_amdgcn_perm(f1, f0, 0x07060302u);
}

// ---------- cross-lane helpers ----------
template <int CTRL>
__device__ inline float dpp_add(float v) {
    int x = __builtin_amdgcn_update_dpp(0, __builtin_bit_cast(int, v), CTRL, 0xF, 0xF, true);
    return v + __builtin_bit_cast(float, x);
}
__device__ inline float row16Sum(float v) {          // sum over lanes sharing l>>4
    v = dpp_add<0xB1>(v);
    v = dpp_add<0x4E>(v);
    v = dpp_add<0x141>(v);
    v = dpp_add<0x140>(v);
    return v;
}
__device__ inline float waveSum64(float v) {
    v = row16Sum(v);
    v += __shfl_xor(v, 16, 64);
    v += __shfl_xor(v, 32, 64);
    return v;
}
// legacy shfl butterfly (kept for mmd path: preserves summation order)
__device__ inline float waveReduceSumOld(float v) {
    #pragma unroll
    for (int off = 32; off > 0; off >>= 1) v += __shfl_xor(v, off, 64);
    return v;
}
__device__ inline float blockReduce128(float v, float* sh2) {  // 128-thread blocks
    v = waveSum64(v);
    int wid = threadIdx.x >> 6;
    if ((threadIdx.x & 63) == 0) sh2[wid] = v;
    __syncthreads();
    float r = sh2[0] + sh2[1];
    __syncthreads();
    return r;
}

// ---------- kernel A: normalize (transposed out) + f2 + zero s_neg + A-pack ----------
__global__ __launch_bounds__(128) void k_prep(const float* __restrict__ img,
                                              const float* __restrict__ txt,
                                              const float* __restrict__ local,
                                              float* imgT, float* txtT,
                                              float* a2i, float* a2t,
                                              float* f2w, float* s_neg,
                                              bf16x8* __restrict__ Apk) {
    __shared__ float sh2[2];
    int bid = blockIdx.x, t = threadIdx.x;
    if (bid < 256) {
        int row = bid & 127, which = bid >> 7;
        if (bid < 4) s_neg[bid * 128 + t] = 0.f;
        const float* src = which ? txt : img;
        float* dstT = which ? txtT : imgT;
        float* a2 = which ? a2t : a2i;
        float v = src[row * D_ + t];
        float s = blockReduce128(v * v, sh2);
        float n = v / sqrtf(s);
        dstT[t * 128 + row] = n;                  // transposed for coalesced mmd stream
        float s2 = blockReduce128(n * n, sh2);
        if (t == 0) a2[row] = s2;
    } else if (bid < 768) {
        int r = bid - 256;                        // 0..511 = (p,b)
        float v = local[(size_t)r * D_ + t];
        float s = blockReduce128(v * v, sh2);
        if (t == 0) f2w[r] = s;
    } else {
        // pack A = local[p] into bf16 MFMA fragments ONCE
        int g = (bid - 768) * 128 + t;            // 0..8191 global fragment id
        int p = g >> 11, f = g & 2047;
        int fl = f & 63, bt = (f >> 6) & 7, kc = f >> 9;
        int row = bt * 16 + (fl & 15);
        int col = kc * 32 + ((fl >> 4) & 3) * 8;
        const float* lp = local + (size_t)p * B_ * D_ + row * D_ + col;
        const uint4 u0 = *(const uint4*)lp;
        const uint4 u1 = *(const uint4*)(lp + 4);
        union { bf16x8 v; unsigned u[4]; } fr;
        fr.u[0] = pack_bf16_trunc(u0.x, u0.y);
        fr.u[1] = pack_bf16_trunc(u0.z, u0.w);
        fr.u[2] = pack_bf16_trunc(u1.x, u1.y);
        fr.u[3] = pack_bf16_trunc(u1.z, u1.w);
        Apk[g] = fr.v;                            // coalesced 16B store, fragment-linear
    }
}

// ---------- k_neg helpers: wave-private register double-buffer pipeline ----------
__device__ __forceinline__ void load_rb(uint4 (&rb)[4][2], const float* cb,
                                        int tl, int n16, int q) {
    const uint4* src = (const uint4*)(cb + (size_t)(tl * 16 + n16) * D_ + q * 8);
    #pragma unroll
    for (int kc = 0; kc < 4; kc++) {
        rb[kc][0] = src[kc * 8];
        rb[kc][1] = src[kc * 8 + 1];
    }
}

__device__ __forceinline__ void compute_tile(const uint4 (&rb)[4][2], int tl, bool valid,
                                             const bf16x8* A_lds, const float* f2l,
                                             float (&sacc)[8][4],
                                             const int* __restrict__ ci,
                                             const int* __restrict__ posi,
                                             int l, int n16, int q) {
    // pack B fragments + row norm
    float c2 = 0.f;
    bf16x8 bfr[4];
    #pragma unroll
    for (int kc = 0; kc < 4; kc++) {
        union { uint4 u; floatx4 f; } a, b;
        a.u = rb[kc][0];
        b.u = rb[kc][1];
        c2 += a.f[0]*a.f[0] + a.f[1]*a.f[1] + a.f[2]*a.f[2] + a.f[3]*a.f[3]
            + b.f[0]*b.f[0] + b.f[1]*b.f[1] + b.f[2]*b.f[2] + b.f[3]*b.f[3];
        union { bf16x8 v; unsigned u[4]; } fr;
        fr.u[0] = pack_bf16_trunc(a.u.x, a.u.y);
        fr.u[1] = pack_bf16_trunc(a.u.z, a.u.w);
        fr.u[2] = pack_bf16_trunc(b.u.x, b.u.y);
        fr.u[3] = pack_bf16_trunc(b.u.z, b.u.w);
        bfr[kc] = fr.v;
    }
    c2 += __shfl_xor(c2, 16, 64);
    c2 += __shfl_xor(c2, 32, 64);
    const float c2v = c2;

    // MFMA: A (128 b-rows) x B-frag (16 m-cols)
    floatx4 acc[8];
    #pragma unroll
    for (int bt = 0; bt < 8; bt++) acc[bt] = (floatx4)(0.f);
    #pragma unroll
    for (int kc = 0; kc < 4; kc++) {
        #pragma unroll
        for (int bt = 0; bt < 8; bt++) {
            bf16x8 af = A_lds[kc * 512 + bt * 64 + l];
            acc[bt] = __builtin_amdgcn_mfma_f32_16x16x32_bf16(af, bfr[kc], acc[bt], 0, 0, 0);
        }
    }

    // underflow-vote fast path
    float dmin = 1e30f;
    #pragma unroll
    for (int bt = 0; bt < 8; bt++) {
        floatx4 f4 = *(const floatx4*)&f2l[bt * 16 + q * 4];
        #pragma unroll
        for (int r = 0; r < 4; r++) {
            float d2 = fmaf(-2.f, acc[bt][r], f4[r] + c2v);
            dmin = fminf(dmin, d2);
        }
    }
    if (valid && __any(dmin < D2_CUT)) {
        // faithful slow path (cold): mask via direct scan; gm < M_ guaranteed by valid
        const int gm = tl * 16 + n16;
        float vm = 1.f;
        for (int ii = 0; ii < B_ * K_; ii++) {
            if (ci[ii] == gm) vm = 0.f;
        }
        for (int ii = 0; ii < B_; ii++) {
            if (posi[ii] == gm) vm = 0.f;
        }
        #pragma unroll
        for (int bt = 0; bt < 8; bt++) {
            floatx4 f4 = *(const floatx4*)&f2l[bt * 16 + q * 4];
            #pragma unroll
            for (int r = 0; r < 4; r++) {
                float d2 = fmaxf(fmaf(-2.f, acc[bt][r], f4[r] + c2v), 0.f);
                if (d2 < D2_CUT) sacc[bt][r] += vm * expf(-SCALE_ * sqrtf(d2));
            }
        }
    }
}

// ---------- kernel B1: neg — persistent wave-private pipelines, no loop barriers ----
// 512 blocks = 2/CU (LDS 33KB, VGPR ~180 under (256,2) -> 8 waves/CU), each wave
// owns 12-13 16-row tiles with a register double-buffer; compiler inserts minimal
// per-register vmcnt waits -> loads continuously in flight, waves drift freely.
__global__ __launch_bounds__(256, 2) void k_neg(const float* __restrict__ centers,
                                                const int* __restrict__ ci,
                                                const int* __restrict__ posi,
                                                const float* __restrict__ f2w,
                                                const bf16x8* __restrict__ Apk,
                                                float* __restrict__ s_neg) {
    __shared__ bf16x8 A_lds[2048];    // 32 KB, fragment order
    __shared__ float f2l[128];
    const int bid = blockIdx.x;
    const int t = threadIdx.x;
    const int w = t >> 6;
    const int l = t & 63;
    const int p = bid >> 7;                       // 128 blocks per p
    const int v = ((bid & 127) << 2) + w;         // wave id in p: 0..511
    const int n16 = l & 15;
    const int q = l >> 4;

    // ---- stage A (pre-packed bf16) to LDS once; f2l once ----
    const bf16x8* Ap = Apk + (p << 11);
    #pragma unroll
    for (int s8 = 0; s8 < 8; s8++) {
        int fb = w * 64 + 256 * s8;               // wave-uniform fragment base
        __builtin_amdgcn_global_load_lds(
            (const __attribute__((address_space(1))) void*)(Ap + fb + l),
            (__attribute__((address_space(3))) void*)(&A_lds[fb]),
            16, 0, 0);
    }
    if (t < 128) f2l[t] = f2w[p * 128 + t];
    __syncthreads();                              // drains A-DMA (vmcnt) + f2l

    const float* cb = centers + (size_t)p * M_ * D_;

    float sacc[8][4];
    #pragma unroll
    for (int bt = 0; bt < 8; bt++)
        #pragma unroll
        for (int r = 0; r < 4; r++) sacc[bt][r] = 0.f;

    // ---- pipelined tile loop: tiles v, v+512, ..., 13 slots (last may be invalid) ----
    uint4 rbA[4][2], rbB[4][2];
    load_rb(rbA, cb, v, n16, q);
    for (int jj = 0; jj < 6; jj++) {
        const int t1 = v + (2 * jj + 1) * WPP;    // always < NT16
        load_rb(rbB, cb, t1, n16, q);
        compute_tile(rbA, v + 2 * jj * WPP, true, A_lds, f2l, sacc, ci, posi, l, n16, q);
        const int t2i = v + (2 * jj + 2) * WPP;
        load_rb(rbA, cb, (t2i < NT16) ? t2i : 0, n16, q);   // jj<5 always valid
        compute_tile(rbB, t1, true, A_lds, f2l, sacc, ci, posi, l, n16, q);
    }
    const int t12 = v + 12 * WPP;
    compute_tile(rbA, t12, t12 < NT16, A_lds, f2l, sacc, ci, posi, l, n16, q);

    // ---- per-wave reduce over m (lanes n16), guarded atomics (fast path: none fire) ----
    #pragma unroll
    for (int bt = 0; bt < 8; bt++) {
        #pragma unroll
        for (int r = 0; r < 4; r++) {
            float s = row16Sum(sacc[bt][r]);
            if (n16 == 0 && s != 0.f)
                atomicAdd(&s_neg[p * 128 + bt * 16 + q * 4 + r], s);
        }
    }
}

// ---------- kernel B2: mmd + pos (small LDS, many blocks/CU, separately profiled) ---
__global__ __launch_bounds__(256) void k_mp(const float* __restrict__ local,
                                            const float* __restrict__ centers,
                                            const float* __restrict__ imgT,
                                            const float* __restrict__ txtT,
                                            const float* __restrict__ a2i,
                                            const float* __restrict__ a2t,
                                            const int* __restrict__ ci,
                                            const int* __restrict__ mvid,
                                            const float* __restrict__ f2w,
                                            float* __restrict__ s_pos,
                                            double* __restrict__ mmd_part,
                                            float* __restrict__ out) {
    __shared__ float ri[128], rt[128], sh2[2];
    const int bid = blockIdx.x;
    const int t = threadIdx.x;
    const int w = t >> 6;
    const int l = t & 63;

    if (bid < MMD_BLOCKS) {
        // ================= mmd (row i); threads 0-127 active, coalesced stream =======
        const int i = bid;
        if (t < 128) {
            ri[t] = imgT[t * 128 + i];            // row i gather (once)
            rt[t] = txtT[t * 128 + i];
        }
        __syncthreads();
        float kxx = 0.f, kyy = 0.f, kxy = 0.f;
        if (t < 128) {
            float dxx = 0.f, dyy = 0.f, dxy = 0.f;
            #pragma unroll 4
            for (int d = 0; d < D_; d++) {
                float rid = ri[d], rtd = rt[d];
                float av = imgT[d * 128 + t];     // coalesced
                float bv = txtT[d * 128 + t];
                dxx = fmaf(rid, av, dxx);
                dyy = fmaf(rtd, bv, dyy);
                dxy = fmaf(rid, bv, dxy);
            }
            kxx = (i == t) ? 0.f : expf(-fmaxf(a2i[i] + a2i[t] - 2.f * dxx, 0.f) * 0.5f);
            kyy = (i == t) ? 0.f : expf(-fmaxf(a2t[i] + a2t[t] - 2.f * dyy, 0.f) * 0.5f);
            kxy = expf(-fmaxf(a2i[i] + a2t[t] - 2.f * dxy, 0.f) * 0.5f);
        }
        float sxx = waveReduceSumOld(kxx);
        float syy = waveReduceSumOld(kyy);
        float sxy = waveReduceSumOld(kxy);
        __syncthreads();
        if (t == 0)  { sh2[0] = sxx; }
        if (t == 64) { sh2[1] = sxx; }
        __syncthreads();
        float txx = sh2[0] + sh2[1];
        __syncthreads();
        if (t == 0)  { sh2[0] = syy; }
        if (t == 64) { sh2[1] = syy; }
        __syncthreads();
        float tyy = sh2[0] + sh2[1];
        __syncthreads();
        if (t == 0)  { sh2[0] = sxy; }
        if (t == 64) { sh2[1] = sxy; }
        __syncthreads();
        float txy = sh2[0] + sh2[1];
        if (t == 0) {
            mmd_part[i] = (double)txx;
            mmd_part[128 + i] = (double)tyy;
            mmd_part[256 + i] = (double)txy;
        }
    } else {
        // ================= pos: one wave per (p,b), 4 per block ======================
        const int pair = (bid - MMD_BLOCKS) * 4 + w;   // 0..511
        const int p = pair >> 7, b = pair & 127;
        const float* f = local + (size_t)pair * D_;
        float f0 = f[l], f1 = f[l + 64];
        float f2v = f2w[pair];
        const float* cb = centers + (size_t)p * M_ * D_;
        float s = 0.f;
        #pragma unroll
        for (int k = 0; k < K_; k++) {
            int idx = ci[b * K_ + k];
            const float* c = cb + (size_t)idx * D_;
            float c0 = c[l], c1 = c[l + 64];
            float p2 = waveSum64(c0 * c0 + c1 * c1);
            float fp = waveSum64(f0 * c0 + f1 * c1);
            float d2 = fmaxf(f2v + p2 - 2.f * fp, 0.f);
            if (d2 < D2_CUT) s += expf(-SCALE_ * sqrtf(d2));   // wave-uniform branch
        }
        if (l == 0) s_pos[pair] = s;
        if (p == 0 && l < K_) {
            int ix = ci[b * K_ + l];
            out[3 + b * K_ + l] = (float)mvid[ix];
        }
    }
}

// ---------- kernel C: final scalars ----------
__global__ __launch_bounds__(512) void k_final(const float* __restrict__ s_pos,
                                               const float* __restrict__ s_neg,
                                               const double* __restrict__ mmd_part,
                                               float* out) {
    __shared__ float red[512];
    __shared__ float lp_[4];
    int t = threadIdx.x;
    float x = logf(s_pos[t]);
    float y = logf(s_neg[t]);
    red[t] = -x + y;
    __syncthreads();
    for (int s = 64; s > 0; s >>= 1) {
        if ((t & 127) < s) red[t] += red[t + s];
        __syncthreads();
    }
    if ((t & 127) == 0) {
        float lv = red[t] / (float)B_;
        if (isnan(lv)) lv = 0.f;
        lp_[t >> 7] = lv;
    }
    __syncthreads();
    if (t == 0) {
        float local_loss = (lp_[0] + lp_[1] + lp_[2] + lp_[3]) / (float)P_;
        double sxx = 0.0, syy = 0.0, sxy = 0.0;
        for (int i = 0; i < 128; i++) {
            sxx += mmd_part[i];
            syy += mmd_part[128 + i];
            sxy += mmd_part[256 + i];
        }
        double denom = 128.0 * 127.0;
        float mmd = (float)(sxx / denom + syy / denom - 2.0 * (sxy / (128.0 * 128.0)));
        out[0] = local_loss + mmd;
        out[1] = local_loss;
        out[2] = mmd;
    }
}

extern "C" void kernel_launch(void* const* d_in, const int* in_sizes, int n_in,
                              void* d_out, int out_size, void* d_ws, size_t ws_size,
                              hipStream_t stream) {
    const float* img     = (const float*)d_in[0];
    const float* txt     = (const float*)d_in[1];
    const float* local   = (const float*)d_in[2];
    const float* centers = (const float*)d_in[3];
    const int*   ci      = (const int*)d_in[4];
    const int*   posi    = (const int*)d_in[5];
    const int*   mvid    = (const int*)d_in[6];
    float* out = (float*)d_out;

    char* ws = (char*)d_ws;
    float*  imgT     = (float*)(ws + 0);
    float*  txtT     = (float*)(ws + 65536);
    float*  a2i      = (float*)(ws + 131072);
    float*  a2t      = (float*)(ws + 131584);
    float*  f2w      = (float*)(ws + 132096);
    float*  s_pos    = (float*)(ws + 134144);
    float*  s_neg    = (float*)(ws + 136192);
    double* mmd_part = (double*)(ws + 138240);
    bf16x8* Apk      = (bf16x8*)(ws + 147456);   // 128 KB, 16B-aligned

    k_prep<<<832, 128, 0, stream>>>(img, txt, local, imgT, txtT, a2i, a2t, f2w, s_neg, Apk);
    k_neg<<<NEG_BLOCKS, 256, 0, stream>>>(centers, ci, posi, f2w, Apk, s_neg);
    k_mp<<<MMD_BLOCKS + POS_BLOCKS, 256, 0, stream>>>(
        local, centers, imgT, txtT, a2i, a2t, ci, mvid, f2w, s_pos, mmd_part, out);
    k_final<<<1, 512, 0, stream>>>(s_pos, s_neg, mmd_part, out);
}

// Round 5
// 324.248 us; speedup vs baseline: 1.0626x; 1.0626x over previous
//
#include <hip/hip_runtime.h>
#include <math.h>

#define B_ 128
#define D_ 128
#define P_ 4
#define M_ 100000
#define K_ 10
#define SCALE_ 10.0f
#define NEG_BLOCKS 512          // 128 blocks per p; 2 wave-pairs per block; 256 pairs per p
#define MMD_BLOCKS 128
#define POS_BLOCKS 128          // 512 (p,b) pairs / 4 waves
#define D2_CUT 120.0f           // d2 >= 120 -> exp(-10*sqrt(d2)) == 0.0f exactly (2^-158)

typedef short bf16x8 __attribute__((ext_vector_type(8)));
typedef float floatx4 __attribute__((ext_vector_type(4)));

// pack two fp32 -> two bf16 (truncate) in one v_perm_b32
__device__ inline unsigned pack_bf16_trunc(unsigned f0, unsigned f1) {
    return __builtin_amdgcn_perm(f1, f0, 0x07060302u);
}

// ---------- cross-lane helpers ----------
template <int CTRL>
__device__ inline float dpp_add(float v) {
    int x = __builtin_amdgcn_update_dpp(0, __builtin_bit_cast(int, v), CTRL, 0xF, 0xF, true);
    return v + __builtin_bit_cast(float, x);
}
__device__ inline float row16Sum(float v) {          // sum over lanes sharing l>>4
    v = dpp_add<0xB1>(v);
    v = dpp_add<0x4E>(v);
    v = dpp_add<0x141>(v);
    v = dpp_add<0x140>(v);
    return v;
}
__device__ inline float waveSum64(float v) {
    v = row16Sum(v);
    v += __shfl_xor(v, 16, 64);
    v += __shfl_xor(v, 32, 64);
    return v;
}
// legacy shfl butterfly (kept for mmd path: preserves summation order)
__device__ inline float waveReduceSumOld(float v) {
    #pragma unroll
    for (int off = 32; off > 0; off >>= 1) v += __shfl_xor(v, off, 64);
    return v;
}
__device__ inline float blockReduce128(float v, float* sh2) {  // 128-thread blocks
    v = waveSum64(v);
    int wid = threadIdx.x >> 6;
    if ((threadIdx.x & 63) == 0) sh2[wid] = v;
    __syncthreads();
    float r = sh2[0] + sh2[1];
    __syncthreads();
    return r;
}

// ---------- kernel A: normalize (transposed out) + f2 + zero s_neg + A-pack ----------
__global__ __launch_bounds__(128) void k_prep(const float* __restrict__ img,
                                              const float* __restrict__ txt,
                                              const float* __restrict__ local,
                                              float* imgT, float* txtT,
                                              float* a2i, float* a2t,
                                              float* f2w, float* s_neg,
                                              bf16x8* __restrict__ Apk) {
    __shared__ float sh2[2];
    int bid = blockIdx.x, t = threadIdx.x;
    if (bid < 256) {
        int row = bid & 127, which = bid >> 7;
        if (bid < 4) s_neg[bid * 128 + t] = 0.f;
        const float* src = which ? txt : img;
        float* dstT = which ? txtT : imgT;
        float* a2 = which ? a2t : a2i;
        float v = src[row * D_ + t];
        float s = blockReduce128(v * v, sh2);
        float n = v / sqrtf(s);
        dstT[t * 128 + row] = n;                  // transposed for coalesced mmd stream
        float s2 = blockReduce128(n * n, sh2);
        if (t == 0) a2[row] = s2;
    } else if (bid < 768) {
        int r = bid - 256;                        // 0..511 = (p,b)
        float v = local[(size_t)r * D_ + t];
        float s = blockReduce128(v * v, sh2);
        if (t == 0) f2w[r] = s;
    } else {
        // pack A = local[p] into bf16 MFMA fragments ONCE
        int g = (bid - 768) * 128 + t;            // 0..8191 global fragment id
        int p = g >> 11, f = g & 2047;
        int fl = f & 63, bt = (f >> 6) & 7, kc = f >> 9;
        int row = bt * 16 + (fl & 15);
        int col = kc * 32 + ((fl >> 4) & 3) * 8;
        const float* lp = local + (size_t)p * B_ * D_ + row * D_ + col;
        const uint4 u0 = *(const uint4*)lp;
        const uint4 u1 = *(const uint4*)(lp + 4);
        union { bf16x8 v; unsigned u[4]; } fr;
        fr.u[0] = pack_bf16_trunc(u0.x, u0.y);
        fr.u[1] = pack_bf16_trunc(u0.z, u0.w);
        fr.u[2] = pack_bf16_trunc(u1.x, u1.y);
        fr.u[3] = pack_bf16_trunc(u1.z, u1.w);
        Apk[g] = fr.v;                            // coalesced 16B store, fragment-linear
    }
}

// ---------- kernel B1: neg — coalesced DMA-to-LDS, wave-pair tiles ----------
// The four previous variants all read centers with lane-stride 512B (16B/lane
// scattered over 16 rows) and all pinned at ~118us = 1.7 TB/s = the random-64B
// sector ceiling. This version reads centers with lane-CONTIGUOUS global_load_lds
// (lane l <- base + l*16, full cachelines) into LDS, and does the 512B-stride
// fragment gather from LDS (XOR swizzle -> structural-minimum bank access).
// Pair of waves shares a 16-row tile; wave h computes bt = h*4..h*4+3.
// A fragments + f2 live in registers (~160 VGPR, (256,2) -> no spill).
__global__ __launch_bounds__(256, 2) void k_neg(const float* __restrict__ centers,
                                                const int* __restrict__ ci,
                                                const int* __restrict__ posi,
                                                const float* __restrict__ f2w,
                                                const bf16x8* __restrict__ Apk,
                                                float* __restrict__ s_neg) {
    __shared__ float Bt[2][3][2048];   // [pair][buf][8KB] = 48 KB total
    const int t = threadIdx.x;
    const int w = t >> 6;
    const int l = t & 63;
    const int bid = blockIdx.x;
    const int p = bid >> 7;                       // 128 blocks per p
    const int g = bid & 127;
    const int pp = w >> 1;                        // pair within block (0,1)
    const int hm = w & 1;                         // member within pair (0,1)
    const int pairid = 2 * g + pp;                // 0..255 within p
    const int nt = (g < 53) ? 25 : 24;            // 6250 = 53*2*25 + 75*2*24 (exact)
    const int n16 = l & 15;
    const int q = l >> 4;

    // ---- A fragments (my bt-half) + f2 quad into registers (once) ----
    const bf16x8* Ap = Apk + (p << 11);
    bf16x8 af[4][4];                              // [kc][bt4]
    #pragma unroll
    for (int kc = 0; kc < 4; kc++)
        #pragma unroll
        for (int b4 = 0; b4 < 4; b4++)
            af[kc][b4] = Ap[kc * 512 + (hm * 4 + b4) * 64 + l];
    floatx4 f2r[4];
    #pragma unroll
    for (int b4 = 0; b4 < 4; b4++)
        f2r[b4] = *(const floatx4*)&f2w[p * 128 + (hm * 4 + b4) * 16 + q * 4];

    // ---- per-lane DMA source offsets: contiguous 1KB/instr, bit-4 pre-swizzle ----
    // LDS image L[x] = T[x ^ (((x>>9)&7)<<4)]  (involution; T = row-major tile)
    unsigned srcoff[4];
    #pragma unroll
    for (int j = 0; j < 4; j++) {
        unsigned x = (unsigned)(hm * 4096 + j * 1024 + l * 16);
        unsigned s = (x >> 9) & 7u;
        srcoff[j] = x ^ (s << 4);                 // flips bit 4 only: coalescing intact
    }

    const char* tb0 = (const char*)(centers + (size_t)p * M_ * D_);
    char* myBt = (char*)&Bt[pp][0][0];

    auto DMA = [&](int tl, int buf) {             // half-tile (4KB) per wave, 4 instrs
        const char* src = tb0 + (size_t)tl * 8192;
        char* dst = myBt + buf * 8192 + hm * 4096;
        #pragma unroll
        for (int j = 0; j < 4; j++) {
            __builtin_amdgcn_global_load_lds(
                (const __attribute__((address_space(1))) void*)(src + srcoff[j]),
                (__attribute__((address_space(3))) void*)(dst + j * 1024),
                16, 0, 0);
        }
    };

    float sacc[4][4];
    #pragma unroll
    for (int b4 = 0; b4 < 4; b4++)
        #pragma unroll
        for (int r = 0; r < 4; r++) sacc[b4][r] = 0.f;

    // ---- prologue: tiles 0,1 in flight; drain tile 0 (keeps tile 1's 4) ----
    DMA(pairid, 0);
    if (nt > 1) DMA(pairid + 256, 1);
    asm volatile("s_waitcnt vmcnt(4)" ::: "memory");
    __builtin_amdgcn_s_barrier();

    int tli = pairid;
    int ib = 0;
    const unsigned sw = (unsigned)((n16 & 7) << 4);
    for (int i = 0; i < nt; i++) {
        // ---- compute tile i from buf ib (swizzled ds_read_b128, conflict-free) ----
        const char* bb = myBt + ib * 8192;
        float c2 = 0.f;
        bf16x8 bfr[4];
        #pragma unroll
        for (int kc = 0; kc < 4; kc++) {
            unsigned t0a = (unsigned)(n16 * 512 + kc * 128 + q * 32);
            union { floatx4 f; uint4 u; } h0, h1;
            h0.f = *(const floatx4*)(bb + (t0a ^ sw));
            h1.f = *(const floatx4*)(bb + ((t0a + 16) ^ sw));
            c2 += h0.f[0]*h0.f[0] + h0.f[1]*h0.f[1] + h0.f[2]*h0.f[2] + h0.f[3]*h0.f[3]
                + h1.f[0]*h1.f[0] + h1.f[1]*h1.f[1] + h1.f[2]*h1.f[2] + h1.f[3]*h1.f[3];
            union { bf16x8 v; unsigned uu[4]; } fr;
            fr.uu[0] = pack_bf16_trunc(h0.u.x, h0.u.y);
            fr.uu[1] = pack_bf16_trunc(h0.u.z, h0.u.w);
            fr.uu[2] = pack_bf16_trunc(h1.u.x, h1.u.y);
            fr.uu[3] = pack_bf16_trunc(h1.u.z, h1.u.w);
            bfr[kc] = fr.v;
        }
        c2 += __shfl_xor(c2, 16, 64);
        c2 += __shfl_xor(c2, 32, 64);
        const float c2v = c2;

        floatx4 acc[4];
        #pragma unroll
        for (int b4 = 0; b4 < 4; b4++) acc[b4] = (floatx4)(0.f);
        #pragma unroll
        for (int kc = 0; kc < 4; kc++) {
            #pragma unroll
            for (int b4 = 0; b4 < 4; b4++)
                acc[b4] = __builtin_amdgcn_mfma_f32_16x16x32_bf16(af[kc][b4], bfr[kc], acc[b4], 0, 0, 0);
        }

        // ---- epilogue: underflow-vote fast path ----
        float dmin = 1e30f;
        #pragma unroll
        for (int b4 = 0; b4 < 4; b4++) {
            #pragma unroll
            for (int r = 0; r < 4; r++) {
                float d2 = fmaf(-2.f, acc[b4][r], f2r[b4][r] + c2v);
                dmin = fminf(dmin, d2);
            }
        }
        if (__any(dmin < D2_CUT)) {
            // faithful slow path (cold): mask via direct scan
            const int gm = tli * 16 + n16;        // always < M_ (exact partition)
            float vm = 1.f;
            for (int ii = 0; ii < B_ * K_; ii++) {
                if (ci[ii] == gm) vm = 0.f;
            }
            for (int ii = 0; ii < B_; ii++) {
                if (posi[ii] == gm) vm = 0.f;
            }
            #pragma unroll
            for (int b4 = 0; b4 < 4; b4++) {
                #pragma unroll
                for (int r = 0; r < 4; r++) {
                    float d2 = fmaxf(fmaf(-2.f, acc[b4][r], f2r[b4][r] + c2v), 0.f);
                    if (d2 < D2_CUT) sacc[b4][r] += vm * expf(-SCALE_ * sqrtf(d2));
                }
            }
        }

        // ---- issue tile i+2 into the buffer freed by compute(i-1); counted wait ----
        if (i + 2 < nt) {
            int b2 = ib + 2; if (b2 >= 3) b2 -= 3;
            DMA(tli + 512, b2);
            asm volatile("s_waitcnt vmcnt(4)" ::: "memory");   // drain tile i+1, keep i+2
        } else if (i + 1 < nt) {
            asm volatile("s_waitcnt vmcnt(0)" ::: "memory");   // drain last tile
        }
        __builtin_amdgcn_s_barrier();             // partner drained too; all past compute(i)

        tli += 256;
        ib = (ib + 1 == 3) ? 0 : ib + 1;
    }

    // ---- per-wave reduce over m (lanes n16); guarded atomics (fast path: none) ----
    #pragma unroll
    for (int b4 = 0; b4 < 4; b4++) {
        #pragma unroll
        for (int r = 0; r < 4; r++) {
            float s = row16Sum(sacc[b4][r]);
            if (n16 == 0 && s != 0.f)
                atomicAdd(&s_neg[p * 128 + (hm * 4 + b4) * 16 + q * 4 + r], s);
        }
    }
}

// ---------- kernel B2: mmd + pos ----------
__global__ __launch_bounds__(256) void k_mp(const float* __restrict__ local,
                                            const float* __restrict__ centers,
                                            const float* __restrict__ imgT,
                                            const float* __restrict__ txtT,
                                            const float* __restrict__ a2i,
                                            const float* __restrict__ a2t,
                                            const int* __restrict__ ci,
                                            const int* __restrict__ mvid,
                                            const float* __restrict__ f2w,
                                            float* __restrict__ s_pos,
                                            double* __restrict__ mmd_part,
                                            float* __restrict__ out) {
    __shared__ float ri[128], rt[128], sh2[2];
    const int bid = blockIdx.x;
    const int t = threadIdx.x;
    const int w = t >> 6;
    const int l = t & 63;

    if (bid < MMD_BLOCKS) {
        // ================= mmd (row i); threads 0-127 active, coalesced stream =======
        const int i = bid;
        if (t < 128) {
            ri[t] = imgT[t * 128 + i];            // row i gather (once)
            rt[t] = txtT[t * 128 + i];
        }
        __syncthreads();
        float kxx = 0.f, kyy = 0.f, kxy = 0.f;
        if (t < 128) {
            float dxx = 0.f, dyy = 0.f, dxy = 0.f;
            #pragma unroll 4
            for (int d = 0; d < D_; d++) {
                float rid = ri[d], rtd = rt[d];
                float av = imgT[d * 128 + t];     // coalesced
                float bv = txtT[d * 128 + t];
                dxx = fmaf(rid, av, dxx);
                dyy = fmaf(rtd, bv, dyy);
                dxy = fmaf(rid, bv, dxy);
            }
            kxx = (i == t) ? 0.f : expf(-fmaxf(a2i[i] + a2i[t] - 2.f * dxx, 0.f) * 0.5f);
            kyy = (i == t) ? 0.f : expf(-fmaxf(a2t[i] + a2t[t] - 2.f * dyy, 0.f) * 0.5f);
            kxy = expf(-fmaxf(a2i[i] + a2t[t] - 2.f * dxy, 0.f) * 0.5f);
        }
        float sxx = waveReduceSumOld(kxx);
        float syy = waveReduceSumOld(kyy);
        float sxy = waveReduceSumOld(kxy);
        __syncthreads();
        if (t == 0)  { sh2[0] = sxx; }
        if (t == 64) { sh2[1] = sxx; }
        __syncthreads();
        float txx = sh2[0] + sh2[1];
        __syncthreads();
        if (t == 0)  { sh2[0] = syy; }
        if (t == 64) { sh2[1] = syy; }
        __syncthreads();
        float tyy = sh2[0] + sh2[1];
        __syncthreads();
        if (t == 0)  { sh2[0] = sxy; }
        if (t == 64) { sh2[1] = sxy; }
        __syncthreads();
        float txy = sh2[0] + sh2[1];
        if (t == 0) {
            mmd_part[i] = (double)txx;
            mmd_part[128 + i] = (double)tyy;
            mmd_part[256 + i] = (double)txy;
        }
    } else {
        // ================= pos: one wave per (p,b), 4 per block ======================
        const int pair = (bid - MMD_BLOCKS) * 4 + w;   // 0..511
        const int p = pair >> 7, b = pair & 127;
        const float* f = local + (size_t)pair * D_;
        float f0 = f[l], f1 = f[l + 64];
        float f2v = f2w[pair];
        const float* cb = centers + (size_t)p * M_ * D_;
        float s = 0.f;
        #pragma unroll
        for (int k = 0; k < K_; k++) {
            int idx = ci[b * K_ + k];
            const float* c = cb + (size_t)idx * D_;
            float c0 = c[l], c1 = c[l + 64];
            float p2 = waveSum64(c0 * c0 + c1 * c1);
            float fp = waveSum64(f0 * c0 + f1 * c1);
            float d2 = fmaxf(f2v + p2 - 2.f * fp, 0.f);
            if (d2 < D2_CUT) s += expf(-SCALE_ * sqrtf(d2));   // wave-uniform branch
        }
        if (l == 0) s_pos[pair] = s;
        if (p == 0 && l < K_) {
            int ix = ci[b * K_ + l];
            out[3 + b * K_ + l] = (float)mvid[ix];
        }
    }
}

// ---------- kernel C: final scalars ----------
__global__ __launch_bounds__(512) void k_final(const float* __restrict__ s_pos,
                                               const float* __restrict__ s_neg,
                                               const double* __restrict__ mmd_part,
                                               float* out) {
    __shared__ float red[512];
    __shared__ float lp_[4];
    int t = threadIdx.x;
    float x = logf(s_pos[t]);
    float y = logf(s_neg[t]);
    red[t] = -x + y;
    __syncthreads();
    for (int s = 64; s > 0; s >>= 1) {
        if ((t & 127) < s) red[t] += red[t + s];
        __syncthreads();
    }
    if ((t & 127) == 0) {
        float lv = red[t] / (float)B_;
        if (isnan(lv)) lv = 0.f;
        lp_[t >> 7] = lv;
    }
    __syncthreads();
    if (t == 0) {
        float local_loss = (lp_[0] + lp_[1] + lp_[2] + lp_[3]) / (float)P_;
        double sxx = 0.0, syy = 0.0, sxy = 0.0;
        for (int i = 0; i < 128; i++) {
            sxx += mmd_part[i];
            syy += mmd_part[128 + i];
            sxy += mmd_part[256 + i];
        }
        double denom = 128.0 * 127.0;
        float mmd = (float)(sxx / denom + syy / denom - 2.0 * (sxy / (128.0 * 128.0)));
        out[0] = local_loss + mmd;
        out[1] = local_loss;
        out[2] = mmd;
    }
}

extern "C" void kernel_launch(void* const* d_in, const int* in_sizes, int n_in,
                              void* d_out, int out_size, void* d_ws, size_t ws_size,
                              hipStream_t stream) {
    const float* img     = (const float*)d_in[0];
    const float* txt     = (const float*)d_in[1];
    const float* local   = (const float*)d_in[2];
    const float* centers = (const float*)d_in[3];
    const int*   ci      = (const int*)d_in[4];
    const int*   posi    = (const int*)d_in[5];
    const int*   mvid    = (const int*)d_in[6];
    float* out = (float*)d_out;

    char* ws = (char*)d_ws;
    float*  imgT     = (float*)(ws + 0);
    float*  txtT     = (float*)(ws + 65536);
    float*  a2i      = (float*)(ws + 131072);
    float*  a2t      = (float*)(ws + 131584);
    float*  f2w      = (float*)(ws + 132096);
    float*  s_pos    = (float*)(ws + 134144);
    float*  s_neg    = (float*)(ws + 136192);
    double* mmd_part = (double*)(ws + 138240);
    bf16x8* Apk      = (bf16x8*)(ws + 147456);   // 128 KB, 16B-aligned

    k_prep<<<832, 128, 0, stream>>>(img, txt, local, imgT, txtT, a2i, a2t, f2w, s_neg, Apk);
    k_neg<<<NEG_BLOCKS, 256, 0, stream>>>(centers, ci, posi, f2w, Apk, s_neg);
    k_mp<<<MMD_BLOCKS + POS_BLOCKS, 256, 0, stream>>>(
        local, centers, imgT, txtT, a2i, a2t, ci, mvid, f2w, s_pos, mmd_part, out);
    k_final<<<1, 512, 0, stream>>>(s_pos, s_neg, mmd_part, out);
}